// Round 12
// baseline (92.276 us; speedup 1.0000x reference)
//
#include <hip/hip_runtime.h>

// Fully-fused LSA, R12 = R10 (best, 86.2us) with the Mb build fused into P0:
// each thread synthesizes its own 8-short chunk of the banded matrix M
// directly (inverse of the verified scatter map: d = k - (24*yi+2+xi);
// dy=d/24, dx=d%24; valid iff dy<5 && dx<5 -> attn[p][5dy+dx], else 0) using
// predicated scalar attn loads. Removes: the Mb zero pass, the separate attn
// stage/scatter phase, and barrier B2 (4 -> 3 barriers) at UNCHANGED LDS
// (76.8KB, 2 blocks/CU -- R11 showed 1 blk/CU double-round regresses).
// Structure:
//   P0: issue halo(12 f4); drain halo->Rt f16 ; build Mb (fused)      B1
//   P1: issue Wv f32; stencil-MFMA f16 (kk-trimmed)                   B2
//   P2: sv(bf16)<-acv (Mb region) ; wvs(bf16)<-Wv (Rt region)         B3
//   P3: Wv-GEMM (bf16) + residual (global fmap) + NT out stores
// B=4, C=128, H=64, W=128, L=25. Grid 512, NT=512, XCD-swizzled.

namespace {
constexpr int Bn = 4, Cn = 128, Hn = 64, Wn = 128, Ln = 25;
constexpr int HWn = Hn * Wn;  // 8192

constexpr int TX = 16, TY = 4;   // 64 px per block
constexpr int RTS = 200;         // Rt row stride in shorts (K=192 + pad)
constexpr int MS  = 200;         // Mb row stride in shorts
constexpr int SVS = 136;         // sv row stride
constexpr int WVS = 136;         // wvs row stride
constexpr int NT  = 512;

typedef __attribute__((ext_vector_type(8))) short short8;
typedef _Float16 half8 __attribute__((ext_vector_type(8)));
typedef __attribute__((ext_vector_type(4))) float f32x4;

__device__ inline unsigned short f2bf(float f) {
    unsigned u = __float_as_uint(f);
    return (unsigned short)((u + 0x7fffu + ((u >> 16) & 1u)) >> 16);  // RNE
}
__device__ inline unsigned short f2h(float f) {
    union { _Float16 h; unsigned short u; } c; c.h = (_Float16)f; return c.u;
}
__device__ inline unsigned pk2h(float a, float b) {
    return (unsigned)f2h(a) | ((unsigned)f2h(b) << 16);
}

__global__ __launch_bounds__(NT, 4) void lsa_fused(
    const float* __restrict__ attn, const float* __restrict__ fmap,
    const float* __restrict__ Wv, const float* __restrict__ gamma,
    float* __restrict__ out)
{
    // region A: Rt f16 [128][200] (51.2KB) -> later wvs bf16 [128][136]
    // region B: Mb f16 [64][200]  (25.6KB) -> later sv  bf16 [64][136]
    __shared__ alignas(16) unsigned short smem[38400];  // 76.8 KB
    unsigned short* const Rt = smem;
    unsigned short* const Mb = smem + 25600;

    const int tid = threadIdx.x;

    // XCD swizzle (verbatim R5): each XCD gets 64 consecutive logical blocks
    // = one batch x 32-row band (2.4MB fmap slice < 4MB L2). Bijective.
    const unsigned bid = blockIdx.x;                 // 0..511
    const unsigned logical = (bid & 7u) * 64u + (bid >> 3);
    const int bx  = logical & 7;        // 8 x-tiles
    const int byz = logical >> 3;
    const int by  = byz & 15;           // 16 y-tiles
    const int b   = byz >> 4;           // 4 batches
    const int x0 = bx * TX;
    const int y0 = by * TY;

    // ---- P0a: issue halo loads (verbatim R5 map: (k6,cp,slot)) ----
    float4 va[6], vb[6];
#pragma unroll
    for (int t = 0; t < 6; ++t) {
        const int i = tid + t * NT;            // 3072 items exactly
        const int k6 = i % 6;
        const int r = i / 6;
        const int cp = r & 63;
        const int s = r >> 6;                  // halo slot 0..7, row y0+s-2
        const int ry = min(max(y0 + s - 2, 0), Hn - 1);
        const int gxb = x0 - 4 + 4 * k6;
        const size_t rowb = ((size_t)(b * Cn + 2 * cp)) * HWn + (size_t)ry * Wn;
        if (gxb < 0) {                       // only bx==0, k6==0: replicate col 0
            const float s0 = fmap[rowb], s1 = fmap[rowb + HWn];
            va[t].x = va[t].y = va[t].z = va[t].w = s0;
            vb[t].x = vb[t].y = vb[t].z = vb[t].w = s1;
        } else if (gxb > Wn - 4) {           // only bx==7, k6==5: replicate col W-1
            const float s0 = fmap[rowb + Wn - 1], s1 = fmap[rowb + HWn + Wn - 1];
            va[t].x = va[t].y = va[t].z = va[t].w = s0;
            vb[t].x = vb[t].y = vb[t].z = vb[t].w = s1;
        } else {
            va[t] = *(const float4*)&fmap[rowb + gxb];
            vb[t] = *(const float4*)&fmap[rowb + HWn + gxb];
        }
    }

    // ---- P0b: drain halo -> Rt f16 ; build Mb chunks (fused zero+scatter) ----
#pragma unroll
    for (int t = 0; t < 6; ++t) {
        const int i = tid + t * NT;
        const int k6 = i % 6;
        const int r = i / 6;
        const int cp = r & 63;
        const int s = r >> 6;
        unsigned short* d0 = &Rt[(2 * cp) * RTS + s * 24 + 4 * k6];
        uint2 wa; wa.x = pk2h(va[t].x, va[t].y); wa.y = pk2h(va[t].z, va[t].w);
        uint2 wb; wb.x = pk2h(vb[t].x, vb[t].y); wb.y = pk2h(vb[t].z, vb[t].w);
        *(uint2*)d0 = wa;
        *(uint2*)(d0 + RTS) = wb;
    }
    // Mb[p][k]: nonzero iff d = k-(24*yi+2+xi) has dy=d/24<5, dx=d%24<5;
    // value = f16(attn[pixel p][5dy+dx]). 1600 chunks of 8 shorts (uint4).
    for (int j = tid; j < 1600; j += NT) {
        const int p  = j / 25;               // M row (pixel) 0..63
        const int c  = j - p * 25;           // chunk 0..24 (k = 8c..8c+7)
        const int yi = p >> 4, xi = p & 15;
        const int base = 24 * yi + 2 + xi;
        const float* arow =
            &attn[((size_t)b * HWn + (size_t)(y0 + yi) * Wn + (x0 + xi)) * Ln];
        unsigned uu[4];
#pragma unroll
        for (int w = 0; w < 4; ++w) {
            float fv[2];
#pragma unroll
            for (int h = 0; h < 2; ++h) {
                const int k2 = c * 8 + 2 * w + h;
                const int d = k2 - base;
                const int dy = d / 24, dx = d - 24 * dy;
                const bool valid = (d >= 0) & (dy < 5) & (dx < 5);
                fv[h] = valid ? arow[5 * dy + dx] : 0.f;
            }
            uu[w] = pk2h(fv[0], fv[1]);
        }
        uint4 v; v.x = uu[0]; v.y = uu[1]; v.z = uu[2]; v.w = uu[3];
        *(uint4*)&Mb[p * MS + c * 8] = v;
    }
    __syncthreads();  // B1: Rt + Mb staged

    // ---- P1: issue Wv f32; stencil-MFMA (kk-trimmed) ----
    float4 wq[8];
#pragma unroll
    for (int t = 0; t < 8; ++t)
        wq[t] = *(const float4*)&Wv[(size_t)(tid + t * NT) * 4];

    const int wave = tid >> 6, lane = tid & 63;
    const int m16 = lane & 15, q = lane >> 4;
    const int row = wave >> 1;            // pixel row 0..3
    const int chalf = wave & 1;           // 64-channel half

    f32x4 acv[4];
#pragma unroll
    for (int t = 0; t < 4; ++t) { f32x4 z = {0.f, 0.f, 0.f, 0.f}; acv[t] = z; }

    // Band for row r: kk in [max(0,r-1), min(5,r+3)]; Mb zero outside -> exact.
    const int kk0 = max(0, row - 1);
    const int kk1 = min(5, row + 3);
#pragma unroll
    for (int kk = 0; kk < 6; ++kk) {
        if (kk >= kk0 && kk <= kk1) {        // wave-uniform guard
            half8 bfr = *(const half8*)&Mb[(row * 16 + m16) * MS + q * 8 + kk * 32];
#pragma unroll
            for (int ct = 0; ct < 4; ++ct) {
                half8 af = *(const half8*)&Rt[(chalf * 64 + ct * 16 + m16) * RTS + q * 8 + kk * 32];
                acv[ct] = __builtin_amdgcn_mfma_f32_16x16x32_f16(af, bfr, acv[ct], 0, 0, 0);
            }
        }
    }
    __syncthreads();  // B2: Rt, Mb dead

    // ---- P2: sv (bf16) <- acv into Mb region ; wvs (bf16) <- wq into Rt region ----
    unsigned short* const sv  = Mb;
    unsigned short* const wvs = Rt;
    {
        const int px = row * 16 + m16;
#pragma unroll
        for (int ct = 0; ct < 4; ++ct) {
            const int c0 = chalf * 64 + ct * 16 + q * 4;   // c = c0 + reg
            uint2 w;
            w.x = (unsigned)f2bf(acv[ct][0]) | ((unsigned)f2bf(acv[ct][1]) << 16);
            w.y = (unsigned)f2bf(acv[ct][2]) | ((unsigned)f2bf(acv[ct][3]) << 16);
            *(uint2*)&sv[px * SVS + c0] = w;
        }
    }
#pragma unroll
    for (int t = 0; t < 8; ++t) {
        const int i4 = tid + t * NT;           // float4 index within Wv
        const int rr = i4 >> 5;                // row (32 float4 per 128-col row)
        const int cc = (i4 & 31) * 4;
        uint2 v;
        v.x = (unsigned)f2bf(wq[t].x) | ((unsigned)f2bf(wq[t].y) << 16);
        v.y = (unsigned)f2bf(wq[t].z) | ((unsigned)f2bf(wq[t].w) << 16);
        *(uint2*)&wvs[rr * WVS + cc] = v;
    }
    __syncthreads();  // B3

    // ---- P3: Wv-GEMM + residual epilogue (verbatim R10; NT out stores) ----
    const int n = (y0 + row) * Wn + x0 + m16;
    const float g = gamma[0];

    short8 bfrag[4];
    {
        const unsigned short* srow = &sv[(row * 16 + m16) * SVS + q * 8];
#pragma unroll
        for (int kk = 0; kk < 4; ++kk) bfrag[kk] = *(const short8*)(srow + kk * 32);
    }
    f32x4 accv[4];
#pragma unroll
    for (int t = 0; t < 4; ++t) { f32x4 z = {0.f, 0.f, 0.f, 0.f}; accv[t] = z; }

#pragma unroll
    for (int t = 0; t < 4; ++t) {
        const int mg = chalf * 4 + t;
        const unsigned short* arow = &wvs[(mg * 16 + m16) * WVS + q * 8];
#pragma unroll
        for (int kk = 0; kk < 4; ++kk) {
            short8 af = *(const short8*)(arow + kk * 32);
            accv[t] = __builtin_amdgcn_mfma_f32_16x16x32_bf16(af, bfrag[kk], accv[t], 0, 0, 0);
        }
    }
#pragma unroll
    for (int t = 0; t < 4; ++t) {
        const int mg = chalf * 4 + t;
#pragma unroll
        for (int r = 0; r < 4; ++r) {
            const int c = mg * 16 + q * 4 + r;
            const size_t idx = ((size_t)(b * Cn + c)) * HWn + n;
            __builtin_nontemporal_store(fmap[idx] + g * accv[t][r], &out[idx]);
        }
    }
}
}  // namespace

extern "C" void kernel_launch(void* const* d_in, const int* in_sizes, int n_in,
                              void* d_out, int out_size, void* d_ws, size_t ws_size,
                              hipStream_t stream) {
    const float* attn  = (const float*)d_in[0];
    const float* fmap  = (const float*)d_in[1];
    const float* Wv    = (const float*)d_in[2];
    const float* gamma = (const float*)d_in[3];
    float* out = (float*)d_out;

    lsa_fused<<<dim3(512), NT, 0, stream>>>(attn, fmap, Wv, gamma, out);
}

// Round 13
// 87.229 us; speedup vs baseline: 1.0579x; 1.0579x over previous
//
#include <hip/hip_runtime.h>

// Fully-fused LSA, R13 = R10 restored verbatim (best: 86.2us, absmax 0.125).
// R11 (barrier cut, 1 blk/CU) and R12 (fused Mb build) both regressed --
// every deviation from this configuration has lost. Structure:
//  - XCD-aware block swizzle (64 logical blocks/XCD = one batch x 32-row band)
//  - P0: issue halo (12 float4) + attn (1 float4 NT) to regs;
//        drain halo -> Rt f16 (channel-major); zero Mb                B1
//  - P1: scatter attn -> Mb (banded matrix, 400 thr)                  B2
//  - P2: issue Wv f32; stencil as MFMA f16, kk-trimmed to the band
//        (kk in [max(0,row-1), min(5,row+3)]; Mb zero outside)        B3
//  - P3: sv(bf16) <- acv (Mb region); wvs(bf16) <- Wv (Rt region)     B4
//  - P4: Wv-GEMM (bf16 MFMA) + residual epilogue, NT out stores
// B=4, C=128, H=64, W=128, L=25. Grid 512, NT=512, LDS 76.8KB, 2 blk/CU.

namespace {
constexpr int Bn = 4, Cn = 128, Hn = 64, Wn = 128, Ln = 25;
constexpr int HWn = Hn * Wn;  // 8192

constexpr int TX = 16, TY = 4;   // 64 px per block
constexpr int RTS = 200;         // Rt row stride in shorts (K=192 + pad)
constexpr int MS  = 200;         // Mb row stride in shorts
constexpr int SVS = 136;         // sv row stride
constexpr int WVS = 136;         // wvs row stride
constexpr int NT  = 512;

typedef __attribute__((ext_vector_type(8))) short short8;
typedef _Float16 half8 __attribute__((ext_vector_type(8)));
typedef __attribute__((ext_vector_type(4))) float f32x4;

__device__ inline unsigned short f2bf(float f) {
    unsigned u = __float_as_uint(f);
    return (unsigned short)((u + 0x7fffu + ((u >> 16) & 1u)) >> 16);  // RNE
}
__device__ inline unsigned short f2h(float f) {
    union { _Float16 h; unsigned short u; } c; c.h = (_Float16)f; return c.u;
}
__device__ inline unsigned pk2h(float a, float b) {
    return (unsigned)f2h(a) | ((unsigned)f2h(b) << 16);
}

__global__ __launch_bounds__(NT, 4) void lsa_fused(
    const float* __restrict__ attn, const float* __restrict__ fmap,
    const float* __restrict__ Wv, const float* __restrict__ gamma,
    float* __restrict__ out)
{
    // region A: Rt f16 [128][200] (51.2KB) -> later wvs bf16 [128][136]
    // region B: Mb f16 [64][200]  (25.6KB) -> later sv  bf16 [64][136]
    __shared__ alignas(16) unsigned short smem[38400];  // 76.8 KB
    unsigned short* const Rt = smem;
    unsigned short* const Mb = smem + 25600;

    const int tid = threadIdx.x;

    // XCD swizzle: each XCD gets 64 consecutive logical blocks
    // = one batch x 32-row band (2.4MB fmap slice < 4MB L2). Bijective.
    const unsigned bid = blockIdx.x;                 // 0..511
    const unsigned logical = (bid & 7u) * 64u + (bid >> 3);
    const int bx  = logical & 7;        // 8 x-tiles
    const int byz = logical >> 3;
    const int by  = byz & 15;           // 16 y-tiles
    const int b   = byz >> 4;           // 4 batches
    const int x0 = bx * TX;
    const int y0 = by * TY;

    // ---- P0a: issue halo loads (verbatim R5 map: (k6,cp,slot)) ----
    float4 va[6], vb[6];
#pragma unroll
    for (int t = 0; t < 6; ++t) {
        const int i = tid + t * NT;            // 3072 items exactly
        const int k6 = i % 6;
        const int r = i / 6;
        const int cp = r & 63;
        const int s = r >> 6;                  // halo slot 0..7, row y0+s-2
        const int ry = min(max(y0 + s - 2, 0), Hn - 1);
        const int gxb = x0 - 4 + 4 * k6;
        const size_t rowb = ((size_t)(b * Cn + 2 * cp)) * HWn + (size_t)ry * Wn;
        if (gxb < 0) {                       // only bx==0, k6==0: replicate col 0
            const float s0 = fmap[rowb], s1 = fmap[rowb + HWn];
            va[t].x = va[t].y = va[t].z = va[t].w = s0;
            vb[t].x = vb[t].y = vb[t].z = vb[t].w = s1;
        } else if (gxb > Wn - 4) {           // only bx==7, k6==5: replicate col W-1
            const float s0 = fmap[rowb + Wn - 1], s1 = fmap[rowb + HWn + Wn - 1];
            va[t].x = va[t].y = va[t].z = va[t].w = s0;
            vb[t].x = vb[t].y = vb[t].z = vb[t].w = s1;
        } else {
            va[t] = *(const float4*)&fmap[rowb + gxb];
            vb[t] = *(const float4*)&fmap[rowb + HWn + gxb];
        }
    }
    // attn: 400 float4 linear, non-temporal (single-touch; keep out of L3).
    const size_t ab = ((size_t)b * HWn + (size_t)y0 * Wn + x0) * Ln;
    f32x4 at_r;
    const int yia = tid / 100, j4 = tid - yia * 100;
    if (tid < 400)
        at_r = __builtin_nontemporal_load(
            (const f32x4*)&attn[ab + (size_t)yia * (Wn * Ln) + (size_t)j4 * 4]);

    // ---- P0b: drain halo -> Rt (f16, channel-major) ; zero Mb ----
#pragma unroll
    for (int t = 0; t < 6; ++t) {
        const int i = tid + t * NT;
        const int k6 = i % 6;
        const int r = i / 6;
        const int cp = r & 63;
        const int s = r >> 6;
        unsigned short* d0 = &Rt[(2 * cp) * RTS + s * 24 + 4 * k6];
        uint2 wa; wa.x = pk2h(va[t].x, va[t].y); wa.y = pk2h(va[t].z, va[t].w);
        uint2 wb; wb.x = pk2h(vb[t].x, vb[t].y); wb.y = pk2h(vb[t].z, vb[t].w);
        *(uint2*)d0 = wa;
        *(uint2*)(d0 + RTS) = wb;
    }
    {
        const uint4 z4 = {0u, 0u, 0u, 0u};
        for (int i = tid; i < 1600; i += NT)   // 1600 uint4 = 25.6KB
            *(uint4*)&Mb[i * 8] = z4;
    }
    __syncthreads();  // B1: Mb zeroed, Rt staged

    // ---- P1: scatter attn -> Mb (banded matrix, f16) ----
    if (tid < 400) {
        const float ae[4] = {at_r[0], at_r[1], at_r[2], at_r[3]};
#pragma unroll
        for (int e = 0; e < 4; ++e) {
            const int t2 = j4 * 4 + e;          // 0..399 within row yia
            const int xi2 = t2 / 25, l = t2 - 25 * xi2;
            const int dy = l / 5, dx = l - 5 * dy;
            // k = (yi+dy)*24 + 2 + xi + dx  (slot s=yi+dy holds row y0+s-2)
            Mb[(yia * 16 + xi2) * MS + (yia + dy) * 24 + 2 + xi2 + dx] = f2h(ae[e]);
        }
    }
    __syncthreads();  // B2: Mb ready

    // ---- P2: issue Wv f32; stencil-MFMA (kk-trimmed) ----
    float4 wq[8];
#pragma unroll
    for (int t = 0; t < 8; ++t)
        wq[t] = *(const float4*)&Wv[(size_t)(tid + t * NT) * 4];

    const int wave = tid >> 6, lane = tid & 63;
    const int m16 = lane & 15, q = lane >> 4;
    const int row = wave >> 1;            // pixel row 0..3
    const int chalf = wave & 1;           // 64-channel half

    f32x4 acv[4];
#pragma unroll
    for (int t = 0; t < 4; ++t) { f32x4 z = {0.f, 0.f, 0.f, 0.f}; acv[t] = z; }

    // Band for row r: kk in [max(0,r-1), min(5,r+3)]; Mb zero outside -> exact.
    const int kk0 = max(0, row - 1);
    const int kk1 = min(5, row + 3);
#pragma unroll
    for (int kk = 0; kk < 6; ++kk) {
        if (kk >= kk0 && kk <= kk1) {        // wave-uniform guard
            half8 bfr = *(const half8*)&Mb[(row * 16 + m16) * MS + q * 8 + kk * 32];
#pragma unroll
            for (int ct = 0; ct < 4; ++ct) {
                half8 af = *(const half8*)&Rt[(chalf * 64 + ct * 16 + m16) * RTS + q * 8 + kk * 32];
                acv[ct] = __builtin_amdgcn_mfma_f32_16x16x32_f16(af, bfr, acv[ct], 0, 0, 0);
            }
        }
    }
    __syncthreads();  // B3: Rt, Mb dead

    // ---- P3: sv (bf16) <- acv into Mb region ; wvs (bf16) <- wq into Rt region ----
    unsigned short* const sv  = Mb;
    unsigned short* const wvs = Rt;
    {
        const int px = row * 16 + m16;
#pragma unroll
        for (int ct = 0; ct < 4; ++ct) {
            const int c0 = chalf * 64 + ct * 16 + q * 4;   // c = c0 + reg
            uint2 w;
            w.x = (unsigned)f2bf(acv[ct][0]) | ((unsigned)f2bf(acv[ct][1]) << 16);
            w.y = (unsigned)f2bf(acv[ct][2]) | ((unsigned)f2bf(acv[ct][3]) << 16);
            *(uint2*)&sv[px * SVS + c0] = w;
        }
    }
#pragma unroll
    for (int t = 0; t < 8; ++t) {
        const int i4 = tid + t * NT;           // float4 index within Wv
        const int rr = i4 >> 5;                // row (32 float4 per 128-col row)
        const int cc = (i4 & 31) * 4;
        uint2 v;
        v.x = (unsigned)f2bf(wq[t].x) | ((unsigned)f2bf(wq[t].y) << 16);
        v.y = (unsigned)f2bf(wq[t].z) | ((unsigned)f2bf(wq[t].w) << 16);
        *(uint2*)&wvs[rr * WVS + cc] = v;
    }
    __syncthreads();  // B4

    // ---- P4: Wv-GEMM + residual epilogue (NT out stores) ----
    const int n = (y0 + row) * Wn + x0 + m16;
    const float g = gamma[0];

    short8 bfrag[4];
    {
        const unsigned short* srow = &sv[(row * 16 + m16) * SVS + q * 8];
#pragma unroll
        for (int kk = 0; kk < 4; ++kk) bfrag[kk] = *(const short8*)(srow + kk * 32);
    }
    f32x4 accv[4];
#pragma unroll
    for (int t = 0; t < 4; ++t) { f32x4 z = {0.f, 0.f, 0.f, 0.f}; accv[t] = z; }

#pragma unroll
    for (int t = 0; t < 4; ++t) {
        const int mg = chalf * 4 + t;
        const unsigned short* arow = &wvs[(mg * 16 + m16) * WVS + q * 8];
#pragma unroll
        for (int kk = 0; kk < 4; ++kk) {
            short8 af = *(const short8*)(arow + kk * 32);
            accv[t] = __builtin_amdgcn_mfma_f32_16x16x32_bf16(af, bfrag[kk], accv[t], 0, 0, 0);
        }
    }
#pragma unroll
    for (int t = 0; t < 4; ++t) {
        const int mg = chalf * 4 + t;
#pragma unroll
        for (int r = 0; r < 4; ++r) {
            const int c = mg * 16 + q * 4 + r;
            const size_t idx = ((size_t)(b * Cn + c)) * HWn + n;
            __builtin_nontemporal_store(fmap[idx] + g * accv[t][r], &out[idx]);
        }
    }
}
}  // namespace

extern "C" void kernel_launch(void* const* d_in, const int* in_sizes, int n_in,
                              void* d_out, int out_size, void* d_ws, size_t ws_size,
                              hipStream_t stream) {
    const float* attn  = (const float*)d_in[0];
    const float* fmap  = (const float*)d_in[1];
    const float* Wv    = (const float*)d_in[2];
    const float* gamma = (const float*)d_in[3];
    float* out = (float*)d_out;

    lsa_fused<<<dim3(512), NT, 0, stream>>>(attn, fmap, Wv, gamma, out);
}